// Round 2
// baseline (1825.647 us; speedup 1.0000x reference)
//
#include <hip/hip_runtime.h>
#include <hip/hip_bf16.h>

#define N_ 50000
#define E_ 1000000
#define R_ 16
#define NB_ 16
#define D_ 128
#define L_ 3
#define G_ 64
#define M_SEG (N_*R_)          // 800000 segments
#define KTOT ((R_+1)*D_)       // 2176 = concat K (16 relations + root)
#define BN 32                  // dst nodes per layer-kernel block
#define LDSK 136               // padded K-row (f16 elems): +8 breaks bank conflicts, keeps 16B align
#define SCAN_BLOCKS ((M_SEG + 1023)/1024)   // 782

typedef _Float16 f16;
typedef _Float16 f16x8 __attribute__((ext_vector_type(8)));
typedef _Float16 f16x4 __attribute__((ext_vector_type(4)));
typedef float f32x4 __attribute__((ext_vector_type(4)));

// ---------------- CSR build ----------------

__global__ __launch_bounds__(256) void k_hist(const int* __restrict__ ei, const int* __restrict__ et,
                                              int* __restrict__ cnt){
  int e = blockIdx.x*256 + threadIdx.x;
  if (e < E_){
    int seg = ei[E_ + e]*R_ + et[e];     // dst*R + type
    atomicAdd(&cnt[seg], 1);
  }
}

__global__ __launch_bounds__(256) void k_scan_sum(const int* __restrict__ cnt, int* __restrict__ bsum){
  __shared__ int sh[256];
  int base = blockIdx.x*1024 + threadIdx.x*4;
  int s = 0;
  #pragma unroll
  for (int j=0;j<4;++j){ int i = base + j; if (i < M_SEG) s += cnt[i]; }
  sh[threadIdx.x] = s; __syncthreads();
  for (int off=128; off>0; off>>=1){
    if (threadIdx.x < off) sh[threadIdx.x] += sh[threadIdx.x+off];
    __syncthreads();
  }
  if (threadIdx.x==0) bsum[blockIdx.x] = sh[0];
}

__global__ __launch_bounds__(256) void k_scan_off(const int* __restrict__ bsum, int* __restrict__ boff){
  __shared__ int sh[256];
  int tid = threadIdx.x;
  int v[4]; int ts = 0;
  #pragma unroll
  for (int j=0;j<4;++j){ int i = tid*4+j; v[j] = (i<SCAN_BLOCKS)? bsum[i] : 0; ts += v[j]; }
  sh[tid] = ts; __syncthreads();
  for (int off=1; off<256; off<<=1){
    int a = sh[tid];
    int b = (tid>=off)? sh[tid-off] : 0;
    __syncthreads(); sh[tid] = a + b; __syncthreads();
  }
  int excl = sh[tid] - ts;
  #pragma unroll
  for (int j=0;j<4;++j){ int i = tid*4+j; if (i<SCAN_BLOCKS) boff[i] = excl; excl += v[j]; }
}

__global__ __launch_bounds__(256) void k_scan_write(const int* __restrict__ cnt, const int* __restrict__ boff,
                                                    int* __restrict__ row_ptr, int* __restrict__ cursor,
                                                    float* __restrict__ inv){
  __shared__ int sh[256];
  int tid = threadIdx.x;
  int base = blockIdx.x*1024 + tid*4;
  int v[4]; int ts = 0;
  #pragma unroll
  for (int j=0;j<4;++j){ int i = base+j; v[j] = (i<M_SEG)? cnt[i] : 0; ts += v[j]; }
  sh[tid] = ts; __syncthreads();
  for (int off=1; off<256; off<<=1){
    int a = sh[tid];
    int b = (tid>=off)? sh[tid-off] : 0;
    __syncthreads(); sh[tid] = a + b; __syncthreads();
  }
  int excl = boff[blockIdx.x] + sh[tid] - ts;
  #pragma unroll
  for (int j=0;j<4;++j){
    int i = base+j;
    if (i < M_SEG){
      row_ptr[i] = excl; cursor[i] = excl;
      int c = v[j];
      inv[i] = 1.0f / (float)(c > 1 ? c : 1);
      if (i == M_SEG-1) row_ptr[M_SEG] = excl + c;
    }
    excl += v[j];
  }
}

__global__ __launch_bounds__(256) void k_place(const int* __restrict__ ei, const int* __restrict__ et,
                                               int* __restrict__ cursor, int* __restrict__ csr_src){
  int e = blockIdx.x*256 + threadIdx.x;
  if (e < E_){
    int seg = ei[E_+e]*R_ + et[e];
    int pos = atomicAdd(&cursor[seg], 1);
    csr_src[pos] = ei[e];                 // src node id, grouped by (dst,rel)
  }
}

// ---------------- input staging ----------------

// 4 nodes/block, 32 lanes per node, float4 copy of the embedding row
__global__ __launch_bounds__(128) void k_gather(const int* __restrict__ ids, const float* __restrict__ emb,
                                                float* __restrict__ x){
  int t = threadIdx.x;
  int n = blockIdx.x*4 + (t >> 5);
  int c = (t & 31) * 4;
  if (n < N_){
    int id = ids[n];
    *(float4*)(x + (size_t)n*D_ + c) = *(const float4*)(emb + (size_t)id*D_ + c);
  }
}

// Wt[l][o][kk] (f16, K-major rows): kk = r*128 + i holds W_r[i][o]; r==16 block holds root[i][o]
__global__ __launch_bounds__(128) void k_wprep(const float* __restrict__ comp, const float* __restrict__ basis,
                                               const float* __restrict__ root, f16* __restrict__ Wt){
  int b = blockIdx.x;
  int o = threadIdx.x;
  int l = b / ((R_+1)*D_);
  int rem = b % ((R_+1)*D_);
  int r = rem / D_;
  int i = rem % D_;
  float acc = 0.f;
  if (r < R_){
    #pragma unroll
    for (int bb=0; bb<NB_; ++bb)
      acc += comp[(l*R_+r)*NB_+bb] * basis[((l*NB_+bb)*D_+i)*D_+o];
  } else {
    acc = root[(l*D_+i)*D_+o];
  }
  Wt[(size_t)l*D_*KTOT + (size_t)o*KTOT + r*D_ + i] = (f16)acc;
}

// ---------------- fused RGCN layer ----------------
// block: 32 dst nodes, 256 threads (4 waves).
// wave w: m-tile mw=w&1 (16 nodes), n-tiles [(w>>1)*4 .. +4) (16 cols each) => out 32x128.
__global__ __launch_bounds__(256) void k_layer(
    const float* __restrict__ xin, float* __restrict__ xout,
    const int* __restrict__ row_ptr, const int* __restrict__ csr_src,
    const float* __restrict__ inv,
    const f16* __restrict__ Wt,
    const float* __restrict__ bias, const float* __restrict__ gamma, const float* __restrict__ beta)
{
  __shared__ __align__(16) f16 mlds[BN][LDSK];    // mean tile (f16), one relation at a time
  __shared__ __align__(16) float olds[BN][D_];    // fp32 out tile for LN epilogue

  const int tid  = threadIdx.x;
  const int lane = tid & 63;
  const int wave = tid >> 6;
  const int nbase = blockIdx.x * BN;
  const int mw  = wave & 1;
  const int ntb = (wave >> 1) * 4;
  const int gid = tid >> 5, l32 = tid & 31;

  f32x4 acc[4];
  f32x4 z = {0.f,0.f,0.f,0.f};
  #pragma unroll
  for (int i=0;i<4;++i) acc[i] = z;

  const int arow = mw*16 + (lane & 15);
  const int kq   = (lane >> 4) * 8;
  // per-wave B column base pointers (o fixed per nt)
  const f16* wcol[4];
  #pragma unroll
  for (int nt=0;nt<4;++nt){
    int o = (ntb + nt)*16 + (lane & 15);
    wcol[nt] = Wt + (size_t)o*KTOT + kq;
  }

  for (int r = 0; r < R_+1; ++r){
    // ---- stage 1: aggregate per-relation means into LDS (f16) ----
    #pragma unroll
    for (int s = 0; s < 4; ++s){
      int nl = gid + s*8;                  // 0..31
      int node = nbase + nl;
      float a0=0.f,a1=0.f,a2=0.f,a3=0.f;
      if (node < N_){
        if (r < R_){
          int seg = node*R_ + r;
          int p0 = row_ptr[seg], p1 = row_ptr[seg+1];
          for (int p = p0; p < p1; ++p){
            int src = csr_src[p];
            float4 vv = *(const float4*)(xin + (size_t)src*D_ + l32*4);
            a0 += vv.x; a1 += vv.y; a2 += vv.z; a3 += vv.w;
          }
          float ic = inv[seg];
          a0*=ic; a1*=ic; a2*=ic; a3*=ic;
        } else {                           // root term: "mean" = x itself
          float4 vv = *(const float4*)(xin + (size_t)node*D_ + l32*4);
          a0=vv.x; a1=vv.y; a2=vv.z; a3=vv.w;
        }
      }
      f16x4 pk = {(f16)a0,(f16)a1,(f16)a2,(f16)a3};
      *(f16x4*)&mlds[nl][l32*4] = pk;
    }
    __syncthreads();
    // ---- stage 2: MFMA accumulate over this relation's K=128 ----
    const int kb = r*D_;
    #pragma unroll
    for (int ks = 0; ks < 4; ++ks){
      f16x8 af = *(const f16x8*)&mlds[arow][ks*32 + kq];
      #pragma unroll
      for (int nt = 0; nt < 4; ++nt){
        f16x8 bf = *(const f16x8*)(wcol[nt] + kb + ks*32);
        acc[nt] = __builtin_amdgcn_mfma_f32_16x16x32_f16(af, bf, acc[nt], 0, 0, 0);
      }
    }
    __syncthreads();
  }

  // ---- epilogue: spill C tiles to LDS, then bias+LN+relu+residual ----
  {
    int rowb = mw*16 + (lane >> 4)*4;      // C/D: col=lane&15, row=(lane>>4)*4+j
    int colb = lane & 15;
    #pragma unroll
    for (int nt=0;nt<4;++nt){
      int col = (ntb+nt)*16 + colb;
      #pragma unroll
      for (int j=0;j<4;++j) olds[rowb+j][col] = acc[nt][j];
    }
  }
  __syncthreads();
  {
    int nl = tid >> 3;                     // 8 threads per node
    int node = nbase + nl;
    int dbase = (tid & 7) * 16;
    float v[16]; float s=0.f, s2=0.f;
    #pragma unroll
    for (int j=0;j<16;++j){
      float t = olds[nl][dbase+j] + bias[dbase+j];
      v[j]=t; s+=t; s2+=t*t;
    }
    #pragma unroll
    for (int off=1; off<8; off<<=1){ s += __shfl_xor(s,off,64); s2 += __shfl_xor(s2,off,64); }
    float mu  = s * (1.f/128.f);
    float var = s2 * (1.f/128.f) - mu*mu;
    float rs  = rsqrtf(var + 1e-5f);
    if (node < N_){
      #pragma unroll
      for (int j=0;j<16;++j){
        int d = dbase + j;
        float o = (v[j]-mu)*rs*gamma[d] + beta[d];
        o = fmaxf(o, 0.f);
        xout[(size_t)node*D_ + d] = xin[(size_t)node*D_ + d] + o;   // residual
      }
    }
  }
}

// ---------------- outputs ----------------

__device__ __forceinline__ int lbound_batch(const int* __restrict__ b, int key){
  int lo=0, hi=N_;
  while (lo<hi){ int mid=(lo+hi)>>1; if (b[mid]<key) lo=mid+1; else hi=mid; }
  return lo;
}

__global__ __launch_bounds__(256) void k_pool(const float* __restrict__ x, const int* __restrict__ batch,
                                              float* __restrict__ gout){
  __shared__ float sh[256];
  int g = blockIdx.x;
  int a = lbound_batch(batch, g);
  int b = lbound_batch(batch, g+1);
  int t = threadIdx.x;
  int d = t & 127, half = t >> 7;
  float s = 0.f;
  for (int n = a + half; n < b; n += 2) s += x[(size_t)n*D_ + d];
  sh[t] = s; __syncthreads();
  if (half == 0){
    float tot = sh[t] + sh[t+128];
    int c = b - a;
    gout[g*D_ + d] = tot / (float)(c > 1 ? c : 1);
  }
}

// ---------------- launch ----------------

extern "C" void kernel_launch(void* const* d_in, const int* in_sizes, int n_in,
                              void* d_out, int out_size, void* d_ws, size_t ws_size,
                              hipStream_t stream){
  const int*   node_ids = (const int*)d_in[0];
  const int*   ei       = (const int*)d_in[1];   // [2,E]: row0=src, row1=dst
  const int*   et       = (const int*)d_in[2];
  const int*   batch    = (const int*)d_in[3];
  const float* emb      = (const float*)d_in[4];
  const float* comp     = (const float*)d_in[5];
  const float* basis    = (const float*)d_in[6];
  const float* root     = (const float*)d_in[7];
  const float* bias     = (const float*)d_in[8];
  const float* gamma    = (const float*)d_in[9];
  const float* beta     = (const float*)d_in[10];
  float* out = (float*)d_out;                    // [N*D] x, then [G*D] graph_embedding

  char* ws = (char*)d_ws;
  size_t off = 0;
  auto alloc = [&](size_t bytes) -> void* {
    void* p = ws + off;
    off = (off + bytes + 255) & ~(size_t)255;
    return p;
  };
  int*   cnt     = (int*)  alloc((size_t)M_SEG*4);
  int*   row_ptr = (int*)  alloc(((size_t)M_SEG+1)*4);
  int*   cursor  = (int*)  alloc((size_t)M_SEG*4);
  float* invc    = (float*)alloc((size_t)M_SEG*4);
  int*   csr_src = (int*)  alloc((size_t)E_*4);
  int*   bsum    = (int*)  alloc((size_t)SCAN_BLOCKS*4);
  int*   boff    = (int*)  alloc((size_t)SCAN_BLOCKS*4);
  float* xA      = (float*)alloc((size_t)N_*D_*4);
  float* xB      = (float*)alloc((size_t)N_*D_*4);
  f16*   Wt      = (f16*)  alloc((size_t)L_*D_*KTOT*2);

  hipMemsetAsync(cnt, 0, (size_t)M_SEG*4, stream);
  k_hist      <<<(E_+255)/256, 256, 0, stream>>>(ei, et, cnt);
  k_scan_sum  <<<SCAN_BLOCKS, 256, 0, stream>>>(cnt, bsum);
  k_scan_off  <<<1, 256, 0, stream>>>(bsum, boff);
  k_scan_write<<<SCAN_BLOCKS, 256, 0, stream>>>(cnt, boff, row_ptr, cursor, invc);
  k_place     <<<(E_+255)/256, 256, 0, stream>>>(ei, et, cursor, csr_src);
  k_gather    <<<(N_+3)/4, 128, 0, stream>>>(node_ids, emb, xA);
  k_wprep     <<<L_*(R_+1)*D_, 128, 0, stream>>>(comp, basis, root, Wt);

  const int LB = (N_ + BN - 1)/BN;
  k_layer<<<LB, 256, 0, stream>>>(xA, xB, row_ptr, csr_src, invc,
                                  Wt + (size_t)0*D_*KTOT, bias+0*D_, gamma+0*D_, beta+0*D_);
  k_layer<<<LB, 256, 0, stream>>>(xB, xA, row_ptr, csr_src, invc,
                                  Wt + (size_t)1*D_*KTOT, bias+1*D_, gamma+1*D_, beta+1*D_);
  k_layer<<<LB, 256, 0, stream>>>(xA, out, row_ptr, csr_src, invc,
                                  Wt + (size_t)2*D_*KTOT, bias+2*D_, gamma+2*D_, beta+2*D_);

  k_pool  <<<G_, 256, 0, stream>>>(out, batch, out + (size_t)N_*D_);
}

// Round 3
// 1235.867 us; speedup vs baseline: 1.4772x; 1.4772x over previous
//
#include <hip/hip_runtime.h>
#include <hip/hip_bf16.h>

#define N_ 50000
#define E_ 1000000
#define R_ 16
#define NB_ 16
#define D_ 128
#define L_ 3
#define G_ 64
#define M_SEG (N_*R_)          // 800000 segments
#define KTOT ((R_+1)*D_)       // 2176
#define SCAN_BLOCKS ((M_SEG + 1023)/1024)   // 782
#define MAXM 450000            // cap on multi-edge segments (actual ~284k)
#define GM 128                 // GEMM M-tile (nodes per block)
#define LDSB 136               // padded LDS B row (f16): 272 B -> 2-way banks (free)

typedef _Float16 f16;
typedef _Float16 f16x8 __attribute__((ext_vector_type(8)));
typedef _Float16 f16x4 __attribute__((ext_vector_type(4)));
typedef _Float16 f16x2 __attribute__((ext_vector_type(2)));
typedef float f32x4 __attribute__((ext_vector_type(4)));

// ---------------- CSR build ----------------

__global__ __launch_bounds__(256) void k_hist(const int* __restrict__ ei, const int* __restrict__ et,
                                              int* __restrict__ cnt){
  int e = blockIdx.x*256 + threadIdx.x;
  if (e < E_){
    int seg = ei[E_ + e]*R_ + et[e];     // dst*R + type
    atomicAdd(&cnt[seg], 1);
  }
}

__global__ __launch_bounds__(256) void k_scan_sum(const int* __restrict__ cnt, int* __restrict__ bsum){
  __shared__ int sh[256];
  int base = blockIdx.x*1024 + threadIdx.x*4;
  int s = 0;
  #pragma unroll
  for (int j=0;j<4;++j){ int i = base + j; if (i < M_SEG) s += cnt[i]; }
  sh[threadIdx.x] = s; __syncthreads();
  for (int off=128; off>0; off>>=1){
    if (threadIdx.x < off) sh[threadIdx.x] += sh[threadIdx.x+off];
    __syncthreads();
  }
  if (threadIdx.x==0) bsum[blockIdx.x] = sh[0];
}

__global__ __launch_bounds__(256) void k_scan_off(const int* __restrict__ bsum, int* __restrict__ boff){
  __shared__ int sh[256];
  int tid = threadIdx.x;
  int v[4]; int ts = 0;
  #pragma unroll
  for (int j=0;j<4;++j){ int i = tid*4+j; v[j] = (i<SCAN_BLOCKS)? bsum[i] : 0; ts += v[j]; }
  sh[tid] = ts; __syncthreads();
  for (int off=1; off<256; off<<=1){
    int a = sh[tid];
    int b = (tid>=off)? sh[tid-off] : 0;
    __syncthreads(); sh[tid] = a + b; __syncthreads();
  }
  int excl = sh[tid] - ts;
  #pragma unroll
  for (int j=0;j<4;++j){ int i = tid*4+j; if (i<SCAN_BLOCKS) boff[i] = excl; excl += v[j]; }
}

__global__ __launch_bounds__(256) void k_scan_write(const int* __restrict__ cnt, const int* __restrict__ boff,
                                                    int* __restrict__ row_ptr, int* __restrict__ cursor,
                                                    float* __restrict__ inv){
  __shared__ int sh[256];
  int tid = threadIdx.x;
  int base = blockIdx.x*1024 + tid*4;
  int v[4]; int ts = 0;
  #pragma unroll
  for (int j=0;j<4;++j){ int i = base+j; v[j] = (i<M_SEG)? cnt[i] : 0; ts += v[j]; }
  sh[tid] = ts; __syncthreads();
  for (int off=1; off<256; off<<=1){
    int a = sh[tid];
    int b = (tid>=off)? sh[tid-off] : 0;
    __syncthreads(); sh[tid] = a + b; __syncthreads();
  }
  int excl = boff[blockIdx.x] + sh[tid] - ts;
  #pragma unroll
  for (int j=0;j<4;++j){
    int i = base+j;
    if (i < M_SEG){
      row_ptr[i] = excl; cursor[i] = excl;
      int c = v[j];
      inv[i] = 1.0f / (float)(c > 1 ? c : 1);
      if (i == M_SEG-1) row_ptr[M_SEG] = excl + c;
    }
    excl += v[j];
  }
}

__global__ __launch_bounds__(256) void k_place(const int* __restrict__ ei, const int* __restrict__ et,
                                               int* __restrict__ cursor, int* __restrict__ csr_src){
  int e = blockIdx.x*256 + threadIdx.x;
  if (e < E_){
    int seg = ei[E_+e]*R_ + et[e];
    int pos = atomicAdd(&cursor[seg], 1);
    csr_src[pos] = ei[e];                 // src node id, grouped by (dst,rel)
  }
}

// idxT[r*N + n]: encoded A-row pointer. bit0: 0 -> x16 table, 1 -> abuf table. val>>1 = row.
// empty -> abuf row 0 (zeros); degree-1 -> x16[src]; multi -> abuf[1+slot]; root (r=16) -> x16[n].
__global__ __launch_bounds__(256) void k_idx(const int* __restrict__ cnt, const int* __restrict__ row_ptr,
                                             const int* __restrict__ csr_src,
                                             int* __restrict__ idxT, int* __restrict__ mlist,
                                             int* __restrict__ mcount){
  int i = blockIdx.x*256 + threadIdx.x;
  if (i < M_SEG){
    int n = i >> 4, r = i & 15;
    int c = cnt[i];
    int v;
    if (c == 0) v = 1;
    else if (c == 1) v = csr_src[row_ptr[i]] << 1;
    else {
      int slot = atomicAdd(mcount, 1);
      if (slot < MAXM){ mlist[slot] = i; v = ((1 + slot) << 1) | 1; }
      else v = 1;
    }
    idxT[r*N_ + n] = v;
  } else if (i < M_SEG + N_){
    int n = i - M_SEG;
    idxT[16*N_ + n] = n << 1;            // root slot
  }
}

// ---------------- input staging ----------------

__global__ __launch_bounds__(128) void k_gather(const int* __restrict__ ids, const float* __restrict__ emb,
                                                float* __restrict__ x, f16* __restrict__ x16){
  int t = threadIdx.x;
  int n = blockIdx.x*4 + (t >> 5);
  int c = (t & 31) * 4;
  if (n < N_){
    int id = ids[n];
    float4 v = *(const float4*)(emb + (size_t)id*D_ + c);
    *(float4*)(x + (size_t)n*D_ + c) = v;
    f16x4 h = {(f16)v.x, (f16)v.y, (f16)v.z, (f16)v.w};
    *(f16x4*)(x16 + (size_t)n*D_ + c) = h;
  }
}

// Wt[l][o][kk] (f16, K-major rows): kk = r*128 + i holds W_r[i][o]; r==16 block holds root[i][o]
__global__ __launch_bounds__(128) void k_wprep(const float* __restrict__ comp, const float* __restrict__ basis,
                                               const float* __restrict__ root, f16* __restrict__ Wt){
  int b = blockIdx.x;
  int o = threadIdx.x;
  int l = b / ((R_+1)*D_);
  int rem = b % ((R_+1)*D_);
  int r = rem / D_;
  int i = rem % D_;
  float acc = 0.f;
  if (r < R_){
    #pragma unroll
    for (int bb=0; bb<NB_; ++bb)
      acc += comp[(l*R_+r)*NB_+bb] * basis[((l*NB_+bb)*D_+i)*D_+o];
  } else {
    acc = root[(l*D_+i)*D_+o];
  }
  Wt[(size_t)l*D_*KTOT + (size_t)o*KTOT + r*D_ + i] = (f16)acc;
}

// ---------------- per-layer: multi-edge segment means ----------------
// one 64-lane wave per multi-edge segment (2 f16 channels/lane), grid-stride.
__global__ __launch_bounds__(256) void k_means(const f16* __restrict__ x16,
                                               const int* __restrict__ row_ptr, const int* __restrict__ csr_src,
                                               const float* __restrict__ inv,
                                               const int* __restrict__ mlist, const int* __restrict__ mcount,
                                               f16* __restrict__ abuf){
  int gw = (blockIdx.x*256 + threadIdx.x) >> 6;
  int lane = threadIdx.x & 63;
  int mc = *mcount; if (mc > MAXM) mc = MAXM;
  int nw = gridDim.x * 4;
  for (int slot = gw; slot < mc; slot += nw){
    int seg = mlist[slot];
    int p0 = row_ptr[seg], p1 = row_ptr[seg+1];
    float a0 = 0.f, a1 = 0.f;
    for (int p = p0; p < p1; ++p){
      int src = csr_src[p];
      f16x2 v = *(const f16x2*)(x16 + (size_t)src*D_ + lane*2);
      a0 += (float)v[0]; a1 += (float)v[1];
    }
    float ic = inv[seg];
    f16x2 o = {(f16)(a0*ic), (f16)(a1*ic)};
    *(f16x2*)(abuf + (size_t)(1+slot)*D_ + lane*2) = o;
  }
}

// ---------------- per-layer: GEMM + LN + relu + residual ----------------
// block: 128 nodes x 128 out cols, 256 threads (4 waves), K streamed over 17 relations.
// A-fragments: direct indexed global loads via idxT (16B/lane). B: LDS slab per relation.
__global__ __launch_bounds__(256) void k_gemm(
    const int* __restrict__ idxT, const f16* __restrict__ x16, const f16* __restrict__ abuf,
    const f16* __restrict__ Wt, const float* __restrict__ xin,
    const float* __restrict__ bias, const float* __restrict__ gamma, const float* __restrict__ beta,
    float* __restrict__ xout, f16* __restrict__ xout16)
{
  __shared__ __align__(16) f16 bsl[D_][LDSB];

  const int tid  = threadIdx.x;
  const int lane = tid & 63;
  const int wave = tid >> 6;
  const int l15  = lane & 15;
  const int quad = lane >> 4;
  const int nbase = blockIdx.x * GM;

  f32x4 acc[2][8];
  f32x4 z = {0.f,0.f,0.f,0.f};
  #pragma unroll
  for (int h=0;h<2;++h)
    #pragma unroll
    for (int nt=0;nt<8;++nt) acc[h][nt] = z;

  int nodeh[2];
  #pragma unroll
  for (int h=0;h<2;++h) nodeh[h] = nbase + (wave*2 + h)*16 + l15;

  const int so = tid >> 4;          // staging o-lane (0..15)
  const int sk = (tid & 15) * 8;    // staging k-offset (f16 elems)

  for (int r = 0; r < R_+1; ++r){
    __syncthreads();                // protect previous iteration's bsl reads
    // stage B slab: Wt[o][r*128 .. +128] -> bsl[o][0..128)
    #pragma unroll
    for (int oo = 0; oo < 8; ++oo){
      int orow = oo*16 + so;
      f16x8 w = *(const f16x8*)(Wt + (size_t)orow*KTOT + r*D_ + sk);
      *(f16x8*)&bsl[orow][sk] = w;
    }
    __syncthreads();

    // A row bases for this relation
    const f16* ab[2];
    #pragma unroll
    for (int h=0;h<2;++h){
      int node = nodeh[h];
      int aidx = (node < N_) ? idxT[r*N_ + node] : 1;
      ab[h] = ((aidx & 1) ? abuf : x16) + (size_t)(aidx >> 1) * D_;
    }

    #pragma unroll
    for (int ks = 0; ks < 4; ++ks){
      f16x8 af0 = *(const f16x8*)(ab[0] + ks*32 + quad*8);
      f16x8 af1 = *(const f16x8*)(ab[1] + ks*32 + quad*8);
      #pragma unroll
      for (int nt = 0; nt < 8; ++nt){
        f16x8 bf = *(const f16x8*)&bsl[nt*16 + l15][ks*32 + quad*8];
        acc[0][nt] = __builtin_amdgcn_mfma_f32_16x16x32_f16(af0, bf, acc[0][nt], 0, 0, 0);
        acc[1][nt] = __builtin_amdgcn_mfma_f32_16x16x32_f16(af1, bf, acc[1][nt], 0, 0, 0);
      }
    }
  }

  // epilogue: per-row LN across the 128 cols held by this quad's 16 lanes x 8 n-tiles
  float bv[8], gv[8], btv[8];
  #pragma unroll
  for (int nt=0;nt<8;++nt){
    int col = nt*16 + l15;
    bv[nt] = bias[col]; gv[nt] = gamma[col]; btv[nt] = beta[col];
  }
  #pragma unroll
  for (int h=0;h<2;++h){
    #pragma unroll
    for (int j=0;j<4;++j){
      int rowl = (wave*2 + h)*16 + quad*4 + j;   // C/D: col=lane&15, row=quad*4+reg
      int node = nbase + rowl;
      float t[8]; float s=0.f, s2=0.f;
      #pragma unroll
      for (int nt=0;nt<8;++nt){
        float v = acc[h][nt][j] + bv[nt];
        t[nt] = v; s += v; s2 += v*v;
      }
      #pragma unroll
      for (int m=1;m<16;m<<=1){ s += __shfl_xor(s,m,64); s2 += __shfl_xor(s2,m,64); }
      float mu  = s * (1.f/128.f);
      float var = s2 * (1.f/128.f) - mu*mu;
      float rs  = rsqrtf(var + 1e-5f);
      if (node < N_){
        #pragma unroll
        for (int nt=0;nt<8;++nt){
          int col = nt*16 + l15;
          float o = (t[nt]-mu)*rs*gv[nt] + btv[nt];
          o = fmaxf(o, 0.f);
          float res = xin[(size_t)node*D_ + col] + o;
          xout[(size_t)node*D_ + col] = res;
          xout16[(size_t)node*D_ + col] = (f16)res;
        }
      }
    }
  }
}

// ---------------- outputs ----------------

__device__ __forceinline__ int lbound_batch(const int* __restrict__ b, int key){
  int lo=0, hi=N_;
  while (lo<hi){ int mid=(lo+hi)>>1; if (b[mid]<key) lo=mid+1; else hi=mid; }
  return lo;
}

__global__ __launch_bounds__(256) void k_pool(const float* __restrict__ x, const int* __restrict__ batch,
                                              float* __restrict__ gout){
  __shared__ float sh[256];
  int g = blockIdx.x;
  int a = lbound_batch(batch, g);
  int b = lbound_batch(batch, g+1);
  int t = threadIdx.x;
  int d = t & 127, half = t >> 7;
  float s = 0.f;
  for (int n = a + half; n < b; n += 2) s += x[(size_t)n*D_ + d];
  sh[t] = s; __syncthreads();
  if (half == 0){
    float tot = sh[t] + sh[t+128];
    int c = b - a;
    gout[g*D_ + d] = tot / (float)(c > 1 ? c : 1);
  }
}

// ---------------- launch ----------------

extern "C" void kernel_launch(void* const* d_in, const int* in_sizes, int n_in,
                              void* d_out, int out_size, void* d_ws, size_t ws_size,
                              hipStream_t stream){
  const int*   node_ids = (const int*)d_in[0];
  const int*   ei       = (const int*)d_in[1];   // [2,E]: row0=src, row1=dst
  const int*   et       = (const int*)d_in[2];
  const int*   batch    = (const int*)d_in[3];
  const float* emb      = (const float*)d_in[4];
  const float* comp     = (const float*)d_in[5];
  const float* basis    = (const float*)d_in[6];
  const float* root     = (const float*)d_in[7];
  const float* bias     = (const float*)d_in[8];
  const float* gamma    = (const float*)d_in[9];
  const float* beta     = (const float*)d_in[10];
  float* out = (float*)d_out;                    // [N*D] x, then [G*D] graph_embedding

  char* ws = (char*)d_ws;
  size_t off = 0;
  auto alloc = [&](size_t bytes) -> void* {
    void* p = ws + off;
    off = (off + bytes + 255) & ~(size_t)255;
    return p;
  };
  int*   cnt     = (int*)  alloc((size_t)M_SEG*4);
  int*   row_ptr = (int*)  alloc(((size_t)M_SEG+1)*4);
  int*   cursor  = (int*)  alloc((size_t)M_SEG*4);
  float* invc    = (float*)alloc((size_t)M_SEG*4);
  int*   csr_src = (int*)  alloc((size_t)E_*4);
  int*   bsum    = (int*)  alloc((size_t)SCAN_BLOCKS*4);
  int*   boff    = (int*)  alloc((size_t)SCAN_BLOCKS*4);
  int*   idxT    = (int*)  alloc((size_t)(R_+1)*N_*4);
  int*   mlist   = (int*)  alloc((size_t)MAXM*4);
  int*   mcount  = (int*)  alloc(256);
  float* xA      = (float*)alloc((size_t)N_*D_*4);
  float* xB      = (float*)alloc((size_t)N_*D_*4);
  f16*   xA16    = (f16*)  alloc((size_t)N_*D_*2);
  f16*   xB16    = (f16*)  alloc((size_t)N_*D_*2);
  f16*   Wt      = (f16*)  alloc((size_t)L_*D_*KTOT*2);
  f16*   abuf    = (f16*)  alloc((size_t)(MAXM+1)*D_*2);

  hipMemsetAsync(cnt, 0, (size_t)M_SEG*4, stream);
  hipMemsetAsync(mcount, 0, 256, stream);
  hipMemsetAsync(abuf, 0, (size_t)D_*2, stream);   // zero-row (abuf slot 0)

  k_hist      <<<(E_+255)/256, 256, 0, stream>>>(ei, et, cnt);
  k_scan_sum  <<<SCAN_BLOCKS, 256, 0, stream>>>(cnt, bsum);
  k_scan_off  <<<1, 256, 0, stream>>>(bsum, boff);
  k_scan_write<<<SCAN_BLOCKS, 256, 0, stream>>>(cnt, boff, row_ptr, cursor, invc);
  k_place     <<<(E_+255)/256, 256, 0, stream>>>(ei, et, cursor, csr_src);
  k_idx       <<<(M_SEG+N_+255)/256, 256, 0, stream>>>(cnt, row_ptr, csr_src, idxT, mlist, mcount);
  k_gather    <<<(N_+3)/4, 128, 0, stream>>>(node_ids, emb, xA, xA16);
  k_wprep     <<<L_*(R_+1)*D_, 128, 0, stream>>>(comp, basis, root, Wt);

  const int GB = (N_ + GM - 1)/GM;   // 391
  // layer 0: xA -> xB
  k_means<<<4096, 256, 0, stream>>>(xA16, row_ptr, csr_src, invc, mlist, mcount, abuf);
  k_gemm <<<GB, 256, 0, stream>>>(idxT, xA16, abuf, Wt + (size_t)0*D_*KTOT, xA,
                                  bias+0*D_, gamma+0*D_, beta+0*D_, xB, xB16);
  // layer 1: xB -> xA
  k_means<<<4096, 256, 0, stream>>>(xB16, row_ptr, csr_src, invc, mlist, mcount, abuf);
  k_gemm <<<GB, 256, 0, stream>>>(idxT, xB16, abuf, Wt + (size_t)1*D_*KTOT, xB,
                                  bias+1*D_, gamma+1*D_, beta+1*D_, xA, xA16);
  // layer 2: xA -> out (x16 to scratch xB16, unused afterwards)
  k_means<<<4096, 256, 0, stream>>>(xA16, row_ptr, csr_src, invc, mlist, mcount, abuf);
  k_gemm <<<GB, 256, 0, stream>>>(idxT, xA16, abuf, Wt + (size_t)2*D_*KTOT, xA,
                                  bias+2*D_, gamma+2*D_, beta+2*D_, out, xB16);

  k_pool <<<G_, 256, 0, stream>>>(out, batch, out + (size_t)N_*D_);
}